// Round 10
// baseline (15.224 us; speedup 1.0000x reference)
//
#include <hip/hip_runtime.h>

#define N 4096
#define BLOCK 256             // 4 waves/block, 2 particles per wave -> 8 i/block
#define NB (N / 8)            // 512 blocks, 2 per CU
#define NSTEP (N / 64)        // 64 j-steps per wave (one j per lane per step)

// Single-dispatch kernel, LDS-pipe optimized:
//  - q staged as float4 records (x,y,z,0) -> one ds_read_b128 per j (vs 3x b32)
//  - each wave owns TWO i's -> LDS reads amortized over 2 force chains
//  - 6-step shfl_xor butterflies reduce both (fx,fy,fz) sets; lane 0 stores
//  - dq = p/m folded in (24 elements per block, loads issued pre-barrier)
__global__ __launch_bounds__(BLOCK, 2)
void lj_single_kernel(const float* __restrict__ q, const float* __restrict__ p,
                      const float* __restrict__ m, float* __restrict__ out) {
    __shared__ float4 qs4[N];            // 64 KB, 16B records
    const int tid  = threadIdx.x;
    const int lane = tid & 63;
    const int wave = tid >> 6;           // 0..3
    const int i1   = blockIdx.x * 8 + wave * 2;
    const int i2   = i1 + 1;

    // own particle positions: wave-uniform -> scalar loads
    const float qx1 = q[i1*3+0], qy1 = q[i1*3+1], qz1 = q[i1*3+2];
    const float qx2 = q[i2*3+0], qy2 = q[i2*3+1], qz2 = q[i2*3+2];

    // dq tail inputs: issue global loads early, overlap with staging
    const int dq_n = (N * 3) / NB;       // 24
    float pv = 0.f, mv = 1.f;
    int u = 0;
    if (tid < dq_n) {
        u  = blockIdx.x * dq_n + tid;
        pv = p[u];
        mv = m[u / 3];
    }

    // stage q -> float4 records: thread t handles 4 records per pass from
    // 3 coalesced float4 loads (12 floats = 4 records), 4 passes.
    {
        const float4* __restrict__ q4 = (const float4*)q;
        #pragma unroll
        for (int k = 0; k < 4; ++k) {
            const int g  = k * BLOCK + tid;      // group of 4 records
            const float4 a = q4[g*3 + 0];        // floats 12g+0..3
            const float4 b = q4[g*3 + 1];        // floats 12g+4..7
            const float4 c = q4[g*3 + 2];        // floats 12g+8..11
            qs4[g*4 + 0] = make_float4(a.x, a.y, a.z, 0.f);
            qs4[g*4 + 1] = make_float4(a.w, b.x, b.y, 0.f);
            qs4[g*4 + 2] = make_float4(b.z, b.w, c.x, 0.f);
            qs4[g*4 + 3] = make_float4(c.y, c.z, c.w, 0.f);
        }
    }
    __syncthreads();

    float fx1 = 0.f, fy1 = 0.f, fz1 = 0.f;
    float fx2 = 0.f, fy2 = 0.f, fz2 = 0.f;
    const int sd1 = i1 >> 6;             // diag windows (usually equal)
    const int sd2 = i2 >> 6;
    const float4* __restrict__ qsl = qs4 + lane;

    #pragma unroll 4
    for (int st = 0; st < NSTEP; ++st) {
        const float4 r = qsl[st * 64];   // ds_read_b128, imm offset st*1024
        // chain 1
        const float dx1 = qx1 - r.x;
        const float dy1 = qy1 - r.y;
        const float dz1 = qz1 - r.z;
        const float r21 = fmaf(dx1, dx1, fmaf(dy1, dy1, dz1 * dz1));
        const float a1  = __builtin_amdgcn_rcpf(r21);  // r^-2
        const float b1  = a1 * a1;                     // r^-4
        const float c1  = b1 * a1;                     // r^-6
        const float d1  = b1 * b1;                     // r^-8
        float s1 = d1 * fmaf(-48.0f, c1, 24.0f);       // 24 r^-8 - 48 r^-14
        // chain 2
        const float dx2 = qx2 - r.x;
        const float dy2 = qy2 - r.y;
        const float dz2 = qz2 - r.z;
        const float r22 = fmaf(dx2, dx2, fmaf(dy2, dy2, dz2 * dz2));
        const float a2  = __builtin_amdgcn_rcpf(r22);
        const float b2  = a2 * a2;
        const float c2  = b2 * a2;
        const float d2  = b2 * b2;
        float s2 = d2 * fmaf(-48.0f, c2, 24.0f);
        // diagonal masks: wave-uniform branches, 1-2 of 64 steps
        if (st == sd1) s1 = (st * 64 + lane == i1) ? 0.0f : s1;
        if (st == sd2) s2 = (st * 64 + lane == i2) ? 0.0f : s2;
        fx1 = fmaf(s1, dx1, fx1);
        fy1 = fmaf(s1, dy1, fy1);
        fz1 = fmaf(s1, dz1, fz1);
        fx2 = fmaf(s2, dx2, fx2);
        fy2 = fmaf(s2, dy2, fy2);
        fz2 = fmaf(s2, dz2, fz2);
    }

    // in-register wave reductions (fixed order -> deterministic)
    #pragma unroll
    for (int off = 32; off > 0; off >>= 1) {
        fx1 += __shfl_xor(fx1, off, 64);
        fy1 += __shfl_xor(fy1, off, 64);
        fz1 += __shfl_xor(fz1, off, 64);
        fx2 += __shfl_xor(fx2, off, 64);
        fy2 += __shfl_xor(fy2, off, 64);
        fz2 += __shfl_xor(fz2, off, 64);
    }
    if (lane == 0) {
        out[N*3 + i1*3 + 0] = fx1;
        out[N*3 + i1*3 + 1] = fy1;
        out[N*3 + i1*3 + 2] = fz1;
        out[N*3 + i2*3 + 0] = fx2;
        out[N*3 + i2*3 + 1] = fy2;
        out[N*3 + i2*3 + 2] = fz2;
    }

    // dq = p / m (loads already in flight)
    if (tid < dq_n)
        out[u] = pv / mv;
}

extern "C" void kernel_launch(void* const* d_in, const int* in_sizes, int n_in,
                              void* d_out, int out_size, void* d_ws, size_t ws_size,
                              hipStream_t stream) {
    const float* q = (const float*)d_in[0];
    const float* p = (const float*)d_in[1];
    const float* m = (const float*)d_in[2];
    float* out = (float*)d_out;

    lj_single_kernel<<<NB, BLOCK, 0, stream>>>(q, p, m, out);
}